// Round 15
// baseline (126.984 us; speedup 1.0000x reference)
//
#include <hip/hip_runtime.h>
#include <math.h>

#define B_ 2
#define T_ 2048
#define D_ 1024
#define H_ 16
#define HD_ 64
#define EPS_ 1.1920929e-07f
#define VE_SCALE_ 2.0f

#define NX4_ (B_ * T_ * D_ / 4)          // 1048576
#define NS4_ (3 * D_ * D_ / 4)           // 786432
#define NQ4_ (4 * D_ * D_ / 4)           // 1048576
#define NG4_ (H_ * D_ / 4)               // 4096

typedef __bf16 bf16_t;
typedef __bf16 bf16x4 __attribute__((ext_vector_type(4)));
typedef __bf16 bf16x8 __attribute__((ext_vector_type(8)));
typedef float f32x4 __attribute__((ext_vector_type(4)));

__device__ const f32x4 F4ZERO = {0.f, 0.f, 0.f, 0.f};

typedef __attribute__((address_space(1))) const void gvoid_t;
typedef __attribute__((address_space(3))) void lvoid_t;

__device__ __forceinline__ void gl_lds16(const bf16_t* g, bf16_t* l) {
  // async global->LDS, 16B/lane; LDS dest = wave-uniform base + lane*16
  __builtin_amdgcn_global_load_lds((gvoid_t*)g, (lvoid_t*)l, 16, 0, 0);
}

// ------------- single fused f32->bf16 cast ---------------------------------
// regions: x->x_bf, qkvo rows [0,3072)->wq, [3072,4096)->wo, agw/vgw->wg
__global__ __launch_bounds__(256) void cast_all(
    const float* __restrict__ x, const float* __restrict__ qkvo,
    const float* __restrict__ agw, const float* __restrict__ vgw,
    bf16_t* __restrict__ x_bf, bf16_t* __restrict__ wq,
    bf16_t* __restrict__ wo, bf16_t* __restrict__ wg)
{
  const int i = blockIdx.x * 256 + threadIdx.x;
  const float4* src;
  bf16x4* dst;
  if (i < NX4_) {
    src = (const float4*)x + i;
    dst = (bf16x4*)x_bf + i;
  } else if (i < NX4_ + NS4_) {
    const int j = i - NX4_;
    src = (const float4*)qkvo + j;
    dst = (bf16x4*)wq + j;
  } else if (i < NX4_ + NQ4_) {
    const int j = i - NX4_;
    src = (const float4*)qkvo + j;
    dst = (bf16x4*)wo + (j - NS4_);
  } else if (i < NX4_ + NQ4_ + NG4_) {
    const int j = i - NX4_ - NQ4_;
    src = (const float4*)agw + j;
    dst = (bf16x4*)wg + j;
  } else {
    const int j = i - NX4_ - NQ4_ - NG4_;
    src = (const float4*)vgw + j;
    dst = (bf16x4*)wg + NG4_ + j;
  }
  const float4 v = *src;
  bf16x4 o = {(bf16_t)v.x, (bf16_t)v.y, (bf16_t)v.z, (bf16_t)v.w};
  *dst = o;
}

// ---------------- gates GEMV: one block per (b,t) --------------------------
__global__ __launch_bounds__(256) void gates_kernel(
    const bf16_t* __restrict__ x_bf, const bf16_t* __restrict__ wg,
    float* __restrict__ attn_gate, float* __restrict__ ve_gate2)
{
  const int bt = blockIdx.x;
  const int tid = threadIdx.x;
  __shared__ float xs[D_];
  {
    const bf16x4 xv = ((const bf16x4*)(x_bf + (size_t)bt * D_))[tid];
    xs[tid * 4 + 0] = (float)xv[0];
    xs[tid * 4 + 1] = (float)xv[1];
    xs[tid * 4 + 2] = (float)xv[2];
    xs[tid * 4 + 3] = (float)xv[3];
  }
  __syncthreads();
  const int g = tid >> 3, cg = tid & 7;
  const bf16x8* wrow = (const bf16x8*)(wg + (size_t)g * D_);
  float sum = 0.f;
#pragma unroll
  for (int j = 0; j < 16; ++j) {
    const bf16x8 w8 = wrow[cg + 8 * j];
    const float* xp = &xs[(cg + 8 * j) * 8];
#pragma unroll
    for (int e = 0; e < 8; ++e) sum = fmaf((float)w8[e], xp[e], sum);
  }
  sum += __shfl_xor(sum, 1);
  sum += __shfl_xor(sum, 2);
  sum += __shfl_xor(sum, 4);
  if (cg == 0) {
    const float sg = 1.f / (1.f + __expf(-sum));
    if (g < 16) attn_gate[bt * H_ + g] = sg;
    else        ve_gate2[bt * H_ + (g - 16)] = VE_SCALE_ * sg;
  }
}

// ------- QKV GEMM (64x128 tile, 4 waves, 2-phase dbuf) + fused epilogue ----
// Tile 64 rows x 128 cols, wave = 32x64 (acc[2][4]), LDS 24 KB/block ->
// 6 blocks/CU = 24 waves/CU (2x the 128x128 tile's TLP; r14 occupancy was
// 30% with LDS headroom). Per wave per K-step: 3 gl_lds + 8 MFMA.
// Epilogue fuses rmsnorm/rotary (q,k) and ve-augment (v) as in r14.
__global__ __launch_bounds__(256) void gemm_qkv(
    const bf16_t* __restrict__ A, const bf16_t* __restrict__ W,
    const float* __restrict__ ve, const float* __restrict__ cosb,
    const float* __restrict__ sinb, const float* __restrict__ ve_gate2,
    bf16_t* __restrict__ q_bf, bf16_t* __restrict__ k_bf,
    bf16_t* __restrict__ v_bf, int K,
    const float* __restrict__ lam)
{
  const float scale = lam[0];
  __shared__ bf16_t As[2][64][32];
  __shared__ bf16_t Bs[2][128][32];
  const int tid = threadIdx.x;
  const int lane = tid & 63, w = tid >> 6;
  const int lr = lane & 15, lg = lane >> 4;
  const int wr = w >> 1, wc = w & 1;

  const int nwg = gridDim.x * gridDim.y;   // 24*64 = 1536 (%8==0, no tail)
  int bid = blockIdx.y * gridDim.x + blockIdx.x;
  bid = (bid & 7) * (nwg >> 3) + (bid >> 3);
  const int row0 = (bid / gridDim.x) * 64;
  const int col0 = (bid % gridDim.x) * 128;

  // staging: wave w stages A rows [w*16,+16), B rows [w*16,+16) & [64+w*16,+16)
  const int srow = lane >> 2;
  const int scol = (lane & 3) * 8;
  const bf16_t* Ag  = A + (size_t)(row0 + w * 16 + srow) * K + scol;
  const bf16_t* Wg0 = W + (size_t)(col0 + w * 16 + srow) * K + scol;
  const bf16_t* Wg1 = Wg0 + (size_t)64 * K;

  f32x4 acc[2][4];
#pragma unroll
  for (int i = 0; i < 2; ++i)
#pragma unroll
    for (int j = 0; j < 4; ++j) acc[i][j] = F4ZERO;

#define STAGE_(bi, kk)                                \
  do {                                                \
    gl_lds16(Ag + (kk), &As[bi][w * 16][0]);          \
    gl_lds16(Wg0 + (kk), &Bs[bi][w * 16][0]);         \
    gl_lds16(Wg1 + (kk), &Bs[bi][64 + w * 16][0]);    \
  } while (0)

#define COMPUTE_(bi)                                                     \
  do {                                                                   \
    bf16x8 af[2], bfr[4];                                                \
    _Pragma("unroll")                                                    \
    for (int fm = 0; fm < 2; ++fm)                                       \
      af[fm] = *(const bf16x8*)&As[bi][wr * 32 + fm * 16 + lr][lg * 8];  \
    _Pragma("unroll")                                                    \
    for (int fn = 0; fn < 4; ++fn)                                       \
      bfr[fn] = *(const bf16x8*)&Bs[bi][wc * 64 + fn * 16 + lr][lg * 8]; \
    _Pragma("unroll")                                                    \
    for (int fm = 0; fm < 2; ++fm)                                       \
      _Pragma("unroll")                                                  \
      for (int fn = 0; fn < 4; ++fn)                                     \
        acc[fm][fn] = __builtin_amdgcn_mfma_f32_16x16x32_bf16(           \
            af[fm], bfr[fn], acc[fm][fn], 0, 0, 0);                      \
  } while (0)

  STAGE_(0, 0);
  __syncthreads();
  for (int k0 = 0; k0 + 64 <= K; k0 += 64) {
    STAGE_(1, k0 + 32);
    COMPUTE_(0);
    __syncthreads();
    if (k0 + 64 < K) STAGE_(0, k0 + 64);
    COMPUTE_(1);
    __syncthreads();
  }
#undef STAGE_
#undef COMPUTE_

  // fused epilogue: col = wc*64 + fn*16 + lr; row = wr*32 + fm*16 + lg*4 + r
  const int sec = col0 >> 10;              // 0=q, 1=k, 2=v
  const int h = ((col0 & 1023) >> 6) + wc; // wave's head
#pragma unroll
  for (int fm = 0; fm < 2; ++fm) {
#pragma unroll
    for (int r = 0; r < 4; ++r) {
      const int row = row0 + wr * 32 + fm * 16 + lg * 4 + r;  // bt index
      const int b = row >> 11, t = row & (T_ - 1);
      float v0 = acc[fm][0][r] * scale;
      float v1 = acc[fm][1][r] * scale;
      float v2 = acc[fm][2][r] * scale;
      float v3 = acc[fm][3][r] * scale;
      const size_t obase = ((size_t)(b * H_ + h) * T_ + t) * HD_;
      if (sec < 2) {
        float ssq = v0 * v0 + v1 * v1 + v2 * v2 + v3 * v3;
        ssq += __shfl_xor(ssq, 1);
        ssq += __shfl_xor(ssq, 2);
        ssq += __shfl_xor(ssq, 4);
        ssq += __shfl_xor(ssq, 8);
        const float rn = rsqrtf(ssq * (1.f / 64.f) + EPS_);
        v0 *= rn; v1 *= rn; v2 *= rn; v3 *= rn;
        const float c0 = cosb[t * 32 + lr], s0 = sinb[t * 32 + lr];
        const float c1 = cosb[t * 32 + 16 + lr], s1 = sinb[t * 32 + 16 + lr];
        const float o0 = fmaf(v0, c0, v2 * s0);
        const float o2 = fmaf(v2, c0, -v0 * s0);
        const float o1 = fmaf(v1, c1, v3 * s1);
        const float o3 = fmaf(v3, c1, -v1 * s1);
        bf16_t* dst = (sec == 0 ? q_bf : k_bf);
        dst[obase + 0 + lr]  = (bf16_t)o0;
        dst[obase + 16 + lr] = (bf16_t)o1;
        dst[obase + 32 + lr] = (bf16_t)o2;
        dst[obase + 48 + lr] = (bf16_t)o3;
      } else {
        const float g = ve_gate2[row * H_ + h];
        const float* vp = ve + (size_t)row * D_ + h * HD_;
        v0 = fmaf(g, vp[0 + lr], v0);
        v1 = fmaf(g, vp[16 + lr], v1);
        v2 = fmaf(g, vp[32 + lr], v2);
        v3 = fmaf(g, vp[48 + lr], v3);
        v_bf[obase + 0 + lr]  = (bf16_t)v0;
        v_bf[obase + 16 + lr] = (bf16_t)v1;
        v_bf[obase + 32 + lr] = (bf16_t)v2;
        v_bf[obase + 48 + lr] = (bf16_t)v3;
      }
    }
  }
}

// ------- out-projection GEMM: same 64x128 2-phase geometry, f32 out --------
__global__ __launch_bounds__(256) void gemm_bf16(
    const bf16_t* __restrict__ A, const bf16_t* __restrict__ W,
    float* __restrict__ Cout, int M, int N, int K,
    const float* __restrict__ lam, int li)
{
  const float scale = lam[li];
  __shared__ bf16_t As[2][64][32];
  __shared__ bf16_t Bs[2][128][32];
  const int tid = threadIdx.x;
  const int lane = tid & 63, w = tid >> 6;
  const int lr = lane & 15, lg = lane >> 4;
  const int wr = w >> 1, wc = w & 1;

  const int nwg = gridDim.x * gridDim.y;
  int bid = blockIdx.y * gridDim.x + blockIdx.x;
  bid = (bid & 7) * (nwg >> 3) + (bid >> 3);
  const int row0 = (bid / gridDim.x) * 64;
  const int col0 = (bid % gridDim.x) * 128;

  const int srow = lane >> 2;
  const int scol = (lane & 3) * 8;
  const bf16_t* Ag  = A + (size_t)(row0 + w * 16 + srow) * K + scol;
  const bf16_t* Wg0 = W + (size_t)(col0 + w * 16 + srow) * K + scol;
  const bf16_t* Wg1 = Wg0 + (size_t)64 * K;

  f32x4 acc[2][4];
#pragma unroll
  for (int i = 0; i < 2; ++i)
#pragma unroll
    for (int j = 0; j < 4; ++j) acc[i][j] = F4ZERO;

#define STAGE_(bi, kk)                                \
  do {                                                \
    gl_lds16(Ag + (kk), &As[bi][w * 16][0]);          \
    gl_lds16(Wg0 + (kk), &Bs[bi][w * 16][0]);         \
    gl_lds16(Wg1 + (kk), &Bs[bi][64 + w * 16][0]);    \
  } while (0)

#define COMPUTE_(bi)                                                     \
  do {                                                                   \
    bf16x8 af[2], bfr[4];                                                \
    _Pragma("unroll")                                                    \
    for (int fm = 0; fm < 2; ++fm)                                       \
      af[fm] = *(const bf16x8*)&As[bi][wr * 32 + fm * 16 + lr][lg * 8];  \
    _Pragma("unroll")                                                    \
    for (int fn = 0; fn < 4; ++fn)                                       \
      bfr[fn] = *(const bf16x8*)&Bs[bi][wc * 64 + fn * 16 + lr][lg * 8]; \
    _Pragma("unroll")                                                    \
    for (int fm = 0; fm < 2; ++fm)                                       \
      _Pragma("unroll")                                                  \
      for (int fn = 0; fn < 4; ++fn)                                     \
        acc[fm][fn] = __builtin_amdgcn_mfma_f32_16x16x32_bf16(           \
            af[fm], bfr[fn], acc[fm][fn], 0, 0, 0);                      \
  } while (0)

  STAGE_(0, 0);
  __syncthreads();
  for (int k0 = 0; k0 + 64 <= K; k0 += 64) {
    STAGE_(1, k0 + 32);
    COMPUTE_(0);
    __syncthreads();
    if (k0 + 64 < K) STAGE_(0, k0 + 64);
    COMPUTE_(1);
    __syncthreads();
  }
#undef STAGE_
#undef COMPUTE_

#pragma unroll
  for (int fm = 0; fm < 2; ++fm)
#pragma unroll
    for (int fn = 0; fn < 4; ++fn)
#pragma unroll
      for (int r = 0; r < 4; ++r) {
        const int row = row0 + wr * 32 + fm * 16 + lg * 4 + r;
        const int col = col0 + wc * 64 + fn * 16 + lr;
        Cout[(size_t)row * N + col] = acc[fm][fn][r] * scale;
      }
}

// ---------------- MFMA flash attention, doc-block-diagonal ----------------
__global__ __launch_bounds__(256) void attn_mfma(
    const bf16_t* __restrict__ q_buf, const bf16_t* __restrict__ k_tmp,
    const bf16_t* __restrict__ v_buf, const float* __restrict__ attn_gate,
    const int* __restrict__ docs, const float* __restrict__ scale_ptr,
    bf16_t* __restrict__ y_buf)
{
  const int qt = blockIdx.x, bh = blockIdx.y;
  const int b = bh >> 4, h = bh & 15;
  const int tid = threadIdx.x;
  const int w = tid >> 6, lane = tid & 63;
  const int lr = lane & 15, lg = lane >> 4;
  const float scale = scale_ptr[0];
  __shared__ bf16_t Ks[64][72];
  __shared__ bf16_t Vt[64][72];
  __shared__ bf16_t Ps[64][72];
  __shared__ int dk[64];

  const int dlo = docs[qt * 64];
  const unsigned long long bal =
      __ballot((lane <= qt) && (docs[lane * 64 + 63] >= dlo));
  const int ktlo = __ffsll(bal) - 1;

  const bf16_t* qp = q_buf + ((size_t)bh * T_ + qt * 64 + w * 16 + lr) * HD_;
  const bf16x8 aq0 = *(const bf16x8*)(qp + lg * 8);
  const bf16x8 aq1 = *(const bf16x8*)(qp + 32 + lg * 8);
  int qpos_r[4], docq_r[4];
#pragma unroll
  for (int r = 0; r < 4; ++r) {
    qpos_r[r] = qt * 64 + w * 16 + lg * 4 + r;
    docq_r[r] = docs[qpos_r[r]];
  }
  f32x4 acc[4];
#pragma unroll
  for (int fn = 0; fn < 4; ++fn) acc[fn] = F4ZERO;
  float m[4] = {-1e30f, -1e30f, -1e30f, -1e30f};
  float l[4] = {0.f, 0.f, 0.f, 0.f};

#pragma unroll 1
  for (int kt = ktlo; kt <= qt; ++kt) {
    __syncthreads();
#pragma unroll
    for (int i = 0; i < 2; ++i) {
      const int idx = i * 256 + tid;
      const int krow = idx >> 3;
      const int c8 = (idx & 7) << 3;
      const int gk = kt * 64 + krow;
      const int gks = (((c8 & 16) != 0) && gk > 0) ? gk - 1 : gk;
      *(bf16x8*)&Ks[krow][c8] =
          *(const bf16x8*)(k_tmp + ((size_t)bh * T_ + gks) * HD_ + c8);
      const int kpos = idx & 63;
      const int d0 = (idx >> 6) << 3;
      const bf16x8 vv =
          *(const bf16x8*)(v_buf + ((size_t)bh * T_ + kt * 64 + kpos) * HD_ + d0);
#pragma unroll
      for (int j = 0; j < 8; ++j) Vt[d0 + j][kpos] = vv[j];
    }
    if (tid < 64) dk[tid] = docs[kt * 64 + tid];
    __syncthreads();

    f32x4 s[4];
#pragma unroll
    for (int fn = 0; fn < 4; ++fn) {
      const bf16x8 bk0 = *(const bf16x8*)&Ks[fn * 16 + lr][lg * 8];
      const bf16x8 bk1 = *(const bf16x8*)&Ks[fn * 16 + lr][32 + lg * 8];
      f32x4 z = F4ZERO;
      z = __builtin_amdgcn_mfma_f32_16x16x32_bf16(aq0, bk0, z, 0, 0, 0);
      s[fn] = __builtin_amdgcn_mfma_f32_16x16x32_bf16(aq1, bk1, z, 0, 0, 0);
    }
    const bool strict = (kt < qt);
#pragma unroll
    for (int fn = 0; fn < 4; ++fn) {
      const int kd = dk[fn * 16 + lr];
      const int kp = kt * 64 + fn * 16 + lr;
#pragma unroll
      for (int r = 0; r < 4; ++r) {
        const bool valid = (kd == docq_r[r]) && (strict || kp <= qpos_r[r]);
        s[fn][r] = valid ? s[fn][r] * scale : -3.0e38f;
      }
    }
#pragma unroll
    for (int r = 0; r < 4; ++r) {
      float cm = fmaxf(fmaxf(s[0][r], s[1][r]), fmaxf(s[2][r], s[3][r]));
      cm = fmaxf(cm, __shfl_xor(cm, 1));
      cm = fmaxf(cm, __shfl_xor(cm, 2));
      cm = fmaxf(cm, __shfl_xor(cm, 4));
      cm = fmaxf(cm, __shfl_xor(cm, 8));
      const float mn = fmaxf(m[r], cm);
      const float sc = __expf(m[r] - mn);
      m[r] = mn;
      const float p0 = __expf(s[0][r] - mn);
      const float p1 = __expf(s[1][r] - mn);
      const float p2 = __expf(s[2][r] - mn);
      const float p3 = __expf(s[3][r] - mn);
      float ps = (p0 + p1) + (p2 + p3);
      ps += __shfl_xor(ps, 1);
      ps += __shfl_xor(ps, 2);
      ps += __shfl_xor(ps, 4);
      ps += __shfl_xor(ps, 8);
      l[r] = l[r] * sc + ps;
      acc[0][r] *= sc; acc[1][r] *= sc; acc[2][r] *= sc; acc[3][r] *= sc;
      const int prow = w * 16 + lg * 4 + r;
      Ps[prow][0 + lr]  = (bf16_t)p0;
      Ps[prow][16 + lr] = (bf16_t)p1;
      Ps[prow][32 + lr] = (bf16_t)p2;
      Ps[prow][48 + lr] = (bf16_t)p3;
    }
    const bf16x8 ap0 = *(const bf16x8*)&Ps[w * 16 + lr][lg * 8];
    const bf16x8 ap1 = *(const bf16x8*)&Ps[w * 16 + lr][32 + lg * 8];
#pragma unroll
    for (int fn = 0; fn < 4; ++fn) {
      const bf16x8 bv0 = *(const bf16x8*)&Vt[fn * 16 + lr][lg * 8];
      const bf16x8 bv1 = *(const bf16x8*)&Vt[fn * 16 + lr][32 + lg * 8];
      acc[fn] = __builtin_amdgcn_mfma_f32_16x16x32_bf16(ap0, bv0, acc[fn], 0, 0, 0);
      acc[fn] = __builtin_amdgcn_mfma_f32_16x16x32_bf16(ap1, bv1, acc[fn], 0, 0, 0);
    }
  }
#pragma unroll
  for (int r = 0; r < 4; ++r) {
    const float inv = attn_gate[(size_t)(b * T_ + qpos_r[r]) * H_ + h] / l[r];
#pragma unroll
    for (int fn = 0; fn < 4; ++fn)
      y_buf[(size_t)(b * T_ + qpos_r[r]) * D_ + h * HD_ + fn * 16 + lr] =
          (bf16_t)(acc[fn][r] * inv);
  }
}

extern "C" void kernel_launch(void* const* d_in, const int* in_sizes, int n_in,
                              void* d_out, int out_size, void* d_ws, size_t ws_size,
                              hipStream_t stream) {
  const float* x    = (const float*)d_in[0];
  const float* ve   = (const float*)d_in[1];
  const float* lam  = (const float*)d_in[2];
  const float* cosb = (const float*)d_in[3];
  const float* sinb = (const float*)d_in[4];
  const float* qkvo = (const float*)d_in[5];
  const float* agw  = (const float*)d_in[6];
  const float* vgw  = (const float*)d_in[7];
  const float* ascl = (const float*)d_in[8];
  const int*   docs = (const int*)d_in[9];
  float* out = (float*)d_out;

  const size_t BT = (size_t)B_ * T_;  // 4096
  float* cur = (float*)d_ws;
  bf16_t* x_bf = (bf16_t*)cur;        cur += BT * D_ / 2;
  bf16_t* wq_bf = (bf16_t*)cur;       cur += (size_t)3 * D_ * D_ / 2;
  bf16_t* wo_bf = (bf16_t*)cur;       cur += (size_t)D_ * D_ / 2;
  bf16_t* wg_bf = (bf16_t*)cur;       cur += (size_t)2 * H_ * D_ / 2;
  bf16_t* q_bf = (bf16_t*)cur;        cur += BT * D_ / 2;
  bf16_t* k_bf = (bf16_t*)cur;        cur += BT * D_ / 2;
  bf16_t* v_bf = (bf16_t*)cur;        cur += BT * D_ / 2;
  bf16_t* y_bf = (bf16_t*)cur;        cur += BT * D_ / 2;
  float* attn_gate = cur;             cur += BT * H_;
  float* ve_gate2 = cur;              cur += BT * H_;

  // 0) single fused cast: x, wq, wo, wg (gate weights)
  cast_all<<<(NX4_ + NQ4_ + 2 * NG4_) / 256, 256, 0, stream>>>(
      x, qkvo, agw, vgw, x_bf, wq_bf, wo_bf, wg_bf);

  // 1) gates GEMV (attn-gate sigmoid, ve-gate 2*sigmoid)
  gates_kernel<<<(int)BT, 256, 0, stream>>>(x_bf, wg_bf, attn_gate, ve_gate2);

  // 2) QKV projection + fused rmsnorm/rotary/v-augment — 1536 blocks = 6/CU
  gemm_qkv<<<dim3(3 * D_ / 128, BT / 64), 256, 0, stream>>>(
      x_bf, wq_bf, ve, cosb, sinb, ve_gate2, q_bf, k_bf, v_bf, D_, lam);

  // 3) MFMA flash attention (doc-block-diagonal skip; key-offset fused)
  attn_mfma<<<dim3(T_ / 64, B_ * H_), 256, 0, stream>>>(
      q_bf, k_bf, v_bf, attn_gate, docs, ascl, y_bf);

  // 4) output projection (f32 out) — 512 blocks = 2/CU
  gemm_bf16<<<dim3(D_ / 128, BT / 64), 256, 0, stream>>>(
      y_bf, wo_bf, out, (int)BT, D_, D_, lam, 1);
}

// Round 16
// 116.758 us; speedup vs baseline: 1.0876x; 1.0876x over previous
//
#include <hip/hip_runtime.h>
#include <math.h>

#define B_ 2
#define T_ 2048
#define D_ 1024
#define H_ 16
#define HD_ 64
#define EPS_ 1.1920929e-07f
#define VE_SCALE_ 2.0f

#define NX4_ (B_ * T_ * D_ / 4)          // 1048576
#define NS4_ (3 * D_ * D_ / 4)           // 786432
#define NQ4_ (4 * D_ * D_ / 4)           // 1048576
#define NG4_ (H_ * D_ / 4)               // 4096

typedef __bf16 bf16_t;
typedef __bf16 bf16x4 __attribute__((ext_vector_type(4)));
typedef __bf16 bf16x8 __attribute__((ext_vector_type(8)));
typedef float f32x4 __attribute__((ext_vector_type(4)));

__device__ const f32x4 F4ZERO = {0.f, 0.f, 0.f, 0.f};

typedef __attribute__((address_space(1))) const void gvoid_t;
typedef __attribute__((address_space(3))) void lvoid_t;

__device__ __forceinline__ void gl_lds16(const bf16_t* g, bf16_t* l) {
  // async global->LDS, 16B/lane; LDS dest = wave-uniform base + lane*16
  __builtin_amdgcn_global_load_lds((gvoid_t*)g, (lvoid_t*)l, 16, 0, 0);
}

// ------------- single fused f32->bf16 cast ---------------------------------
// regions: x->x_bf, qkvo rows [0,3072)->wq, [3072,4096)->wo, agw/vgw->wg
__global__ __launch_bounds__(256) void cast_all(
    const float* __restrict__ x, const float* __restrict__ qkvo,
    const float* __restrict__ agw, const float* __restrict__ vgw,
    bf16_t* __restrict__ x_bf, bf16_t* __restrict__ wq,
    bf16_t* __restrict__ wo, bf16_t* __restrict__ wg)
{
  const int i = blockIdx.x * 256 + threadIdx.x;
  const float4* src;
  bf16x4* dst;
  if (i < NX4_) {
    src = (const float4*)x + i;
    dst = (bf16x4*)x_bf + i;
  } else if (i < NX4_ + NS4_) {
    const int j = i - NX4_;
    src = (const float4*)qkvo + j;
    dst = (bf16x4*)wq + j;
  } else if (i < NX4_ + NQ4_) {
    const int j = i - NX4_;
    src = (const float4*)qkvo + j;
    dst = (bf16x4*)wo + (j - NS4_);
  } else if (i < NX4_ + NQ4_ + NG4_) {
    const int j = i - NX4_ - NQ4_;
    src = (const float4*)agw + j;
    dst = (bf16x4*)wg + j;
  } else {
    const int j = i - NX4_ - NQ4_ - NG4_;
    src = (const float4*)vgw + j;
    dst = (bf16x4*)wg + NG4_ + j;
  }
  const float4 v = *src;
  bf16x4 o = {(bf16_t)v.x, (bf16_t)v.y, (bf16_t)v.z, (bf16_t)v.w};
  *dst = o;
}

// ---------------- gates GEMV: one block per (b,t) --------------------------
__global__ __launch_bounds__(256) void gates_kernel(
    const bf16_t* __restrict__ x_bf, const bf16_t* __restrict__ wg,
    float* __restrict__ attn_gate, float* __restrict__ ve_gate2)
{
  const int bt = blockIdx.x;
  const int tid = threadIdx.x;
  __shared__ float xs[D_];
  {
    const bf16x4 xv = ((const bf16x4*)(x_bf + (size_t)bt * D_))[tid];
    xs[tid * 4 + 0] = (float)xv[0];
    xs[tid * 4 + 1] = (float)xv[1];
    xs[tid * 4 + 2] = (float)xv[2];
    xs[tid * 4 + 3] = (float)xv[3];
  }
  __syncthreads();
  const int g = tid >> 3, cg = tid & 7;
  const bf16x8* wrow = (const bf16x8*)(wg + (size_t)g * D_);
  float sum = 0.f;
#pragma unroll
  for (int j = 0; j < 16; ++j) {
    const bf16x8 w8 = wrow[cg + 8 * j];
    const float* xp = &xs[(cg + 8 * j) * 8];
#pragma unroll
    for (int e = 0; e < 8; ++e) sum = fmaf((float)w8[e], xp[e], sum);
  }
  sum += __shfl_xor(sum, 1);
  sum += __shfl_xor(sum, 2);
  sum += __shfl_xor(sum, 4);
  if (cg == 0) {
    const float sg = 1.f / (1.f + __expf(-sum));
    if (g < 16) attn_gate[bt * H_ + g] = sg;
    else        ve_gate2[bt * H_ + (g - 16)] = VE_SCALE_ * sg;
  }
}

// ------- QKV GEMM (r14-measured 128x128 BK=32 2-phase) + fused epilogue ----
// Each wave's 64-col C group is exactly one head: rmsnorm = 3 adds +
// shfl_xor(1,2,4,8); rotary partner d+32 is register-local (fn <-> fn+2).
// Writes q/k/v bf16 directly in (B,H,T,HD).
__global__ __launch_bounds__(256) void gemm_qkv(
    const bf16_t* __restrict__ A, const bf16_t* __restrict__ W,
    const float* __restrict__ ve, const float* __restrict__ cosb,
    const float* __restrict__ sinb, const float* __restrict__ ve_gate2,
    bf16_t* __restrict__ q_bf, bf16_t* __restrict__ k_bf,
    bf16_t* __restrict__ v_bf, int K,
    const float* __restrict__ lam)
{
  const float scale = lam[0];
  __shared__ bf16_t As[2][128][32];
  __shared__ bf16_t Bs[2][128][32];
  const int tid = threadIdx.x;
  const int lane = tid & 63, w = tid >> 6;
  const int lr = lane & 15, lg = lane >> 4;
  const int wr = w >> 1, wc = w & 1;

  const int nwg = gridDim.x * gridDim.y;   // 24*32 = 768 (%8==0, no tail)
  int bid = blockIdx.y * gridDim.x + blockIdx.x;
  bid = (bid & 7) * (nwg >> 3) + (bid >> 3);
  const int row0 = (bid / gridDim.x) * 128;
  const int col0 = (bid % gridDim.x) * 128;

  const int srow = w * 32 + (lane >> 2);
  const int scol = (lane & 3) * 8;
  const bf16_t* Ag = A + (size_t)(row0 + srow) * K + scol;
  const bf16_t* Wg = W + (size_t)(col0 + srow) * K + scol;
  const size_t r16 = (size_t)16 * K;

  f32x4 acc[4][4];
#pragma unroll
  for (int i = 0; i < 4; ++i)
#pragma unroll
    for (int j = 0; j < 4; ++j) acc[i][j] = F4ZERO;

#define STAGE_(bi, kk)                                    \
  do {                                                    \
    gl_lds16(Ag + (kk), &As[bi][w * 32][0]);              \
    gl_lds16(Ag + r16 + (kk), &As[bi][w * 32 + 16][0]);   \
    gl_lds16(Wg + (kk), &Bs[bi][w * 32][0]);              \
    gl_lds16(Wg + r16 + (kk), &Bs[bi][w * 32 + 16][0]);   \
  } while (0)

#define COMPUTE_(bi)                                                     \
  do {                                                                   \
    bf16x8 af[4], bfr[4];                                                \
    _Pragma("unroll")                                                    \
    for (int fm = 0; fm < 4; ++fm)                                       \
      af[fm] = *(const bf16x8*)&As[bi][wr * 64 + fm * 16 + lr][lg * 8];  \
    _Pragma("unroll")                                                    \
    for (int fn = 0; fn < 4; ++fn)                                       \
      bfr[fn] = *(const bf16x8*)&Bs[bi][wc * 64 + fn * 16 + lr][lg * 8]; \
    _Pragma("unroll")                                                    \
    for (int fm = 0; fm < 4; ++fm)                                       \
      _Pragma("unroll")                                                  \
      for (int fn = 0; fn < 4; ++fn)                                     \
        acc[fm][fn] = __builtin_amdgcn_mfma_f32_16x16x32_bf16(           \
            af[fm], bfr[fn], acc[fm][fn], 0, 0, 0);                      \
  } while (0)

  STAGE_(0, 0);
  __syncthreads();
  for (int k0 = 0; k0 + 64 <= K; k0 += 64) {
    STAGE_(1, k0 + 32);
    COMPUTE_(0);
    __syncthreads();
    if (k0 + 64 < K) STAGE_(0, k0 + 64);
    COMPUTE_(1);
    __syncthreads();
  }
#undef STAGE_
#undef COMPUTE_

  // fused epilogue: col = wc*64 + fn*16 + lr; row = wr*64 + fm*16 + lg*4 + r
  const int sec = col0 >> 10;              // 0=q, 1=k, 2=v
  const int h = ((col0 & 1023) >> 6) + wc; // wave's head
#pragma unroll
  for (int fm = 0; fm < 4; ++fm) {
#pragma unroll
    for (int r = 0; r < 4; ++r) {
      const int row = row0 + wr * 64 + fm * 16 + lg * 4 + r;  // bt index
      const int b = row >> 11, t = row & (T_ - 1);
      float v0 = acc[fm][0][r] * scale;
      float v1 = acc[fm][1][r] * scale;
      float v2 = acc[fm][2][r] * scale;
      float v3 = acc[fm][3][r] * scale;
      const size_t obase = ((size_t)(b * H_ + h) * T_ + t) * HD_;
      if (sec < 2) {
        float ssq = v0 * v0 + v1 * v1 + v2 * v2 + v3 * v3;
        ssq += __shfl_xor(ssq, 1);
        ssq += __shfl_xor(ssq, 2);
        ssq += __shfl_xor(ssq, 4);
        ssq += __shfl_xor(ssq, 8);
        const float rn = rsqrtf(ssq * (1.f / 64.f) + EPS_);
        v0 *= rn; v1 *= rn; v2 *= rn; v3 *= rn;
        const float c0 = cosb[t * 32 + lr], s0 = sinb[t * 32 + lr];
        const float c1 = cosb[t * 32 + 16 + lr], s1 = sinb[t * 32 + 16 + lr];
        const float o0 = fmaf(v0, c0, v2 * s0);
        const float o2 = fmaf(v2, c0, -v0 * s0);
        const float o1 = fmaf(v1, c1, v3 * s1);
        const float o3 = fmaf(v3, c1, -v1 * s1);
        bf16_t* dst = (sec == 0 ? q_bf : k_bf);
        dst[obase + 0 + lr]  = (bf16_t)o0;
        dst[obase + 16 + lr] = (bf16_t)o1;
        dst[obase + 32 + lr] = (bf16_t)o2;
        dst[obase + 48 + lr] = (bf16_t)o3;
      } else {
        const float g = ve_gate2[row * H_ + h];
        const float* vp = ve + (size_t)row * D_ + h * HD_;
        v0 = fmaf(g, vp[0 + lr], v0);
        v1 = fmaf(g, vp[16 + lr], v1);
        v2 = fmaf(g, vp[32 + lr], v2);
        v3 = fmaf(g, vp[48 + lr], v3);
        v_bf[obase + 0 + lr]  = (bf16_t)v0;
        v_bf[obase + 16 + lr] = (bf16_t)v1;
        v_bf[obase + 32 + lr] = (bf16_t)v2;
        v_bf[obase + 48 + lr] = (bf16_t)v3;
      }
    }
  }
}

// ------- out-projection GEMM: 64x128 tile, 2-phase dbuf (r15: 2 blocks/CU,
// saved ~7.6 us vs 128x128's 1 block/CU at N=1024), f32 out ----------------
__global__ __launch_bounds__(256) void gemm_bf16(
    const bf16_t* __restrict__ A, const bf16_t* __restrict__ W,
    float* __restrict__ Cout, int M, int N, int K,
    const float* __restrict__ lam, int li)
{
  const float scale = lam[li];
  __shared__ bf16_t As[2][64][32];
  __shared__ bf16_t Bs[2][128][32];
  const int tid = threadIdx.x;
  const int lane = tid & 63, w = tid >> 6;
  const int lr = lane & 15, lg = lane >> 4;
  const int wr = w >> 1, wc = w & 1;

  const int nwg = gridDim.x * gridDim.y;
  int bid = blockIdx.y * gridDim.x + blockIdx.x;
  bid = (bid & 7) * (nwg >> 3) + (bid >> 3);
  const int row0 = (bid / gridDim.x) * 64;
  const int col0 = (bid % gridDim.x) * 128;

  const int srow = lane >> 2;
  const int scol = (lane & 3) * 8;
  const bf16_t* Ag  = A + (size_t)(row0 + w * 16 + srow) * K + scol;
  const bf16_t* Wg0 = W + (size_t)(col0 + w * 16 + srow) * K + scol;
  const bf16_t* Wg1 = Wg0 + (size_t)64 * K;

  f32x4 acc[2][4];
#pragma unroll
  for (int i = 0; i < 2; ++i)
#pragma unroll
    for (int j = 0; j < 4; ++j) acc[i][j] = F4ZERO;

#define STAGE_(bi, kk)                                \
  do {                                                \
    gl_lds16(Ag + (kk), &As[bi][w * 16][0]);          \
    gl_lds16(Wg0 + (kk), &Bs[bi][w * 16][0]);         \
    gl_lds16(Wg1 + (kk), &Bs[bi][64 + w * 16][0]);    \
  } while (0)

#define COMPUTE_(bi)                                                     \
  do {                                                                   \
    bf16x8 af[2], bfr[4];                                                \
    _Pragma("unroll")                                                    \
    for (int fm = 0; fm < 2; ++fm)                                       \
      af[fm] = *(const bf16x8*)&As[bi][wr * 32 + fm * 16 + lr][lg * 8];  \
    _Pragma("unroll")                                                    \
    for (int fn = 0; fn < 4; ++fn)                                       \
      bfr[fn] = *(const bf16x8*)&Bs[bi][wc * 64 + fn * 16 + lr][lg * 8]; \
    _Pragma("unroll")                                                    \
    for (int fm = 0; fm < 2; ++fm)                                       \
      _Pragma("unroll")                                                  \
      for (int fn = 0; fn < 4; ++fn)                                     \
        acc[fm][fn] = __builtin_amdgcn_mfma_f32_16x16x32_bf16(           \
            af[fm], bfr[fn], acc[fm][fn], 0, 0, 0);                      \
  } while (0)

  STAGE_(0, 0);
  __syncthreads();
  for (int k0 = 0; k0 + 64 <= K; k0 += 64) {
    STAGE_(1, k0 + 32);
    COMPUTE_(0);
    __syncthreads();
    if (k0 + 64 < K) STAGE_(0, k0 + 64);
    COMPUTE_(1);
    __syncthreads();
  }
#undef STAGE_
#undef COMPUTE_

#pragma unroll
  for (int fm = 0; fm < 2; ++fm)
#pragma unroll
    for (int fn = 0; fn < 4; ++fn)
#pragma unroll
      for (int r = 0; r < 4; ++r) {
        const int row = row0 + wr * 32 + fm * 16 + lg * 4 + r;
        const int col = col0 + wc * 64 + fn * 16 + lr;
        Cout[(size_t)row * N + col] = acc[fm][fn][r] * scale;
      }
}

// ---------------- MFMA flash attention, doc-block-diagonal ----------------
__global__ __launch_bounds__(256) void attn_mfma(
    const bf16_t* __restrict__ q_buf, const bf16_t* __restrict__ k_tmp,
    const bf16_t* __restrict__ v_buf, const float* __restrict__ attn_gate,
    const int* __restrict__ docs, const float* __restrict__ scale_ptr,
    bf16_t* __restrict__ y_buf)
{
  const int qt = blockIdx.x, bh = blockIdx.y;
  const int b = bh >> 4, h = bh & 15;
  const int tid = threadIdx.x;
  const int w = tid >> 6, lane = tid & 63;
  const int lr = lane & 15, lg = lane >> 4;
  const float scale = scale_ptr[0];
  __shared__ bf16_t Ks[64][72];
  __shared__ bf16_t Vt[64][72];
  __shared__ bf16_t Ps[64][72];
  __shared__ int dk[64];

  const int dlo = docs[qt * 64];
  const unsigned long long bal =
      __ballot((lane <= qt) && (docs[lane * 64 + 63] >= dlo));
  const int ktlo = __ffsll(bal) - 1;

  const bf16_t* qp = q_buf + ((size_t)bh * T_ + qt * 64 + w * 16 + lr) * HD_;
  const bf16x8 aq0 = *(const bf16x8*)(qp + lg * 8);
  const bf16x8 aq1 = *(const bf16x8*)(qp + 32 + lg * 8);
  int qpos_r[4], docq_r[4];
#pragma unroll
  for (int r = 0; r < 4; ++r) {
    qpos_r[r] = qt * 64 + w * 16 + lg * 4 + r;
    docq_r[r] = docs[qpos_r[r]];
  }
  f32x4 acc[4];
#pragma unroll
  for (int fn = 0; fn < 4; ++fn) acc[fn] = F4ZERO;
  float m[4] = {-1e30f, -1e30f, -1e30f, -1e30f};
  float l[4] = {0.f, 0.f, 0.f, 0.f};

#pragma unroll 1
  for (int kt = ktlo; kt <= qt; ++kt) {
    __syncthreads();
#pragma unroll
    for (int i = 0; i < 2; ++i) {
      const int idx = i * 256 + tid;
      const int krow = idx >> 3;
      const int c8 = (idx & 7) << 3;
      const int gk = kt * 64 + krow;
      const int gks = (((c8 & 16) != 0) && gk > 0) ? gk - 1 : gk;
      *(bf16x8*)&Ks[krow][c8] =
          *(const bf16x8*)(k_tmp + ((size_t)bh * T_ + gks) * HD_ + c8);
      const int kpos = idx & 63;
      const int d0 = (idx >> 6) << 3;
      const bf16x8 vv =
          *(const bf16x8*)(v_buf + ((size_t)bh * T_ + kt * 64 + kpos) * HD_ + d0);
#pragma unroll
      for (int j = 0; j < 8; ++j) Vt[d0 + j][kpos] = vv[j];
    }
    if (tid < 64) dk[tid] = docs[kt * 64 + tid];
    __syncthreads();

    f32x4 s[4];
#pragma unroll
    for (int fn = 0; fn < 4; ++fn) {
      const bf16x8 bk0 = *(const bf16x8*)&Ks[fn * 16 + lr][lg * 8];
      const bf16x8 bk1 = *(const bf16x8*)&Ks[fn * 16 + lr][32 + lg * 8];
      f32x4 z = F4ZERO;
      z = __builtin_amdgcn_mfma_f32_16x16x32_bf16(aq0, bk0, z, 0, 0, 0);
      s[fn] = __builtin_amdgcn_mfma_f32_16x16x32_bf16(aq1, bk1, z, 0, 0, 0);
    }
    const bool strict = (kt < qt);
#pragma unroll
    for (int fn = 0; fn < 4; ++fn) {
      const int kd = dk[fn * 16 + lr];
      const int kp = kt * 64 + fn * 16 + lr;
#pragma unroll
      for (int r = 0; r < 4; ++r) {
        const bool valid = (kd == docq_r[r]) && (strict || kp <= qpos_r[r]);
        s[fn][r] = valid ? s[fn][r] * scale : -3.0e38f;
      }
    }
#pragma unroll
    for (int r = 0; r < 4; ++r) {
      float cm = fmaxf(fmaxf(s[0][r], s[1][r]), fmaxf(s[2][r], s[3][r]));
      cm = fmaxf(cm, __shfl_xor(cm, 1));
      cm = fmaxf(cm, __shfl_xor(cm, 2));
      cm = fmaxf(cm, __shfl_xor(cm, 4));
      cm = fmaxf(cm, __shfl_xor(cm, 8));
      const float mn = fmaxf(m[r], cm);
      const float sc = __expf(m[r] - mn);
      m[r] = mn;
      const float p0 = __expf(s[0][r] - mn);
      const float p1 = __expf(s[1][r] - mn);
      const float p2 = __expf(s[2][r] - mn);
      const float p3 = __expf(s[3][r] - mn);
      float ps = (p0 + p1) + (p2 + p3);
      ps += __shfl_xor(ps, 1);
      ps += __shfl_xor(ps, 2);
      ps += __shfl_xor(ps, 4);
      ps += __shfl_xor(ps, 8);
      l[r] = l[r] * sc + ps;
      acc[0][r] *= sc; acc[1][r] *= sc; acc[2][r] *= sc; acc[3][r] *= sc;
      const int prow = w * 16 + lg * 4 + r;
      Ps[prow][0 + lr]  = (bf16_t)p0;
      Ps[prow][16 + lr] = (bf16_t)p1;
      Ps[prow][32 + lr] = (bf16_t)p2;
      Ps[prow][48 + lr] = (bf16_t)p3;
    }
    const bf16x8 ap0 = *(const bf16x8*)&Ps[w * 16 + lr][lg * 8];
    const bf16x8 ap1 = *(const bf16x8*)&Ps[w * 16 + lr][32 + lg * 8];
#pragma unroll
    for (int fn = 0; fn < 4; ++fn) {
      const bf16x8 bv0 = *(const bf16x8*)&Vt[fn * 16 + lr][lg * 8];
      const bf16x8 bv1 = *(const bf16x8*)&Vt[fn * 16 + lr][32 + lg * 8];
      acc[fn] = __builtin_amdgcn_mfma_f32_16x16x32_bf16(ap0, bv0, acc[fn], 0, 0, 0);
      acc[fn] = __builtin_amdgcn_mfma_f32_16x16x32_bf16(ap1, bv1, acc[fn], 0, 0, 0);
    }
  }
#pragma unroll
  for (int r = 0; r < 4; ++r) {
    const float inv = attn_gate[(size_t)(b * T_ + qpos_r[r]) * H_ + h] / l[r];
#pragma unroll
    for (int fn = 0; fn < 4; ++fn)
      y_buf[(size_t)(b * T_ + qpos_r[r]) * D_ + h * HD_ + fn * 16 + lr] =
          (bf16_t)(acc[fn][r] * inv);
  }
}

extern "C" void kernel_launch(void* const* d_in, const int* in_sizes, int n_in,
                              void* d_out, int out_size, void* d_ws, size_t ws_size,
                              hipStream_t stream) {
  const float* x    = (const float*)d_in[0];
  const float* ve   = (const float*)d_in[1];
  const float* lam  = (const float*)d_in[2];
  const float* cosb = (const float*)d_in[3];
  const float* sinb = (const float*)d_in[4];
  const float* qkvo = (const float*)d_in[5];
  const float* agw  = (const float*)d_in[6];
  const float* vgw  = (const float*)d_in[7];
  const float* ascl = (const float*)d_in[8];
  const int*   docs = (const int*)d_in[9];
  float* out = (float*)d_out;

  const size_t BT = (size_t)B_ * T_;  // 4096
  float* cur = (float*)d_ws;
  bf16_t* x_bf = (bf16_t*)cur;        cur += BT * D_ / 2;
  bf16_t* wq_bf = (bf16_t*)cur;       cur += (size_t)3 * D_ * D_ / 2;
  bf16_t* wo_bf = (bf16_t*)cur;       cur += (size_t)D_ * D_ / 2;
  bf16_t* wg_bf = (bf16_t*)cur;       cur += (size_t)2 * H_ * D_ / 2;
  bf16_t* q_bf = (bf16_t*)cur;        cur += BT * D_ / 2;
  bf16_t* k_bf = (bf16_t*)cur;        cur += BT * D_ / 2;
  bf16_t* v_bf = (bf16_t*)cur;        cur += BT * D_ / 2;
  bf16_t* y_bf = (bf16_t*)cur;        cur += BT * D_ / 2;
  float* attn_gate = cur;             cur += BT * H_;
  float* ve_gate2 = cur;              cur += BT * H_;

  // 0) single fused cast: x, wq, wo, wg (gate weights)
  cast_all<<<(NX4_ + NQ4_ + 2 * NG4_) / 256, 256, 0, stream>>>(
      x, qkvo, agw, vgw, x_bf, wq_bf, wo_bf, wg_bf);

  // 1) gates GEMV (attn-gate sigmoid, ve-gate 2*sigmoid)
  gates_kernel<<<(int)BT, 256, 0, stream>>>(x_bf, wg_bf, attn_gate, ve_gate2);

  // 2) QKV projection + fused rmsnorm/rotary/v-augment — 768 blocks (128x128)
  gemm_qkv<<<dim3(3 * D_ / 128, BT / 128), 256, 0, stream>>>(
      x_bf, wq_bf, ve, cosb, sinb, ve_gate2, q_bf, k_bf, v_bf, D_, lam);

  // 3) MFMA flash attention (doc-block-diagonal skip; key-offset fused)
  attn_mfma<<<dim3(T_ / 64, B_ * H_), 256, 0, stream>>>(
      q_bf, k_bf, v_bf, attn_gate, docs, ascl, y_bf);

  // 4) output projection (64x128 tile, 512 blocks = 2/CU, f32 out)
  gemm_bf16<<<dim3(D_ / 128, BT / 64), 256, 0, stream>>>(
      y_bf, wo_bf, out, (int)BT, D_, D_, lam, 1);
}

// Round 17
// 113.831 us; speedup vs baseline: 1.1155x; 1.0257x over previous
//
#include <hip/hip_runtime.h>
#include <math.h>

#define B_ 2
#define T_ 2048
#define D_ 1024
#define H_ 16
#define HD_ 64
#define EPS_ 1.1920929e-07f
#define VE_SCALE_ 2.0f

#define NX4_ (B_ * T_ * D_ / 4)          // 1048576
#define NS4_ (3 * D_ * D_ / 4)           // 786432
#define NQ4_ (4 * D_ * D_ / 4)           // 1048576
#define NG4_ (H_ * D_ / 4)               // 4096

typedef __bf16 bf16_t;
typedef __bf16 bf16x4 __attribute__((ext_vector_type(4)));
typedef __bf16 bf16x8 __attribute__((ext_vector_type(8)));
typedef float f32x4 __attribute__((ext_vector_type(4)));

__device__ const f32x4 F4ZERO = {0.f, 0.f, 0.f, 0.f};

typedef __attribute__((address_space(1))) const void gvoid_t;
typedef __attribute__((address_space(3))) void lvoid_t;

__device__ __forceinline__ void gl_lds16(const bf16_t* g, bf16_t* l) {
  // async global->LDS, 16B/lane; LDS dest = wave-uniform base + lane*16
  __builtin_amdgcn_global_load_lds((gvoid_t*)g, (lvoid_t*)l, 16, 0, 0);
}

// ------------- single fused f32->bf16 cast ---------------------------------
// regions: x->x_bf, qkvo rows [0,3072)->wq, [3072,4096)->wo, agw/vgw->wg
__global__ __launch_bounds__(256) void cast_all(
    const float* __restrict__ x, const float* __restrict__ qkvo,
    const float* __restrict__ agw, const float* __restrict__ vgw,
    bf16_t* __restrict__ x_bf, bf16_t* __restrict__ wq,
    bf16_t* __restrict__ wo, bf16_t* __restrict__ wg)
{
  const int i = blockIdx.x * 256 + threadIdx.x;
  const float4* src;
  bf16x4* dst;
  if (i < NX4_) {
    src = (const float4*)x + i;
    dst = (bf16x4*)x_bf + i;
  } else if (i < NX4_ + NS4_) {
    const int j = i - NX4_;
    src = (const float4*)qkvo + j;
    dst = (bf16x4*)wq + j;
  } else if (i < NX4_ + NQ4_) {
    const int j = i - NX4_;
    src = (const float4*)qkvo + j;
    dst = (bf16x4*)wo + (j - NS4_);
  } else if (i < NX4_ + NQ4_ + NG4_) {
    const int j = i - NX4_ - NQ4_;
    src = (const float4*)agw + j;
    dst = (bf16x4*)wg + j;
  } else {
    const int j = i - NX4_ - NQ4_ - NG4_;
    src = (const float4*)vgw + j;
    dst = (bf16x4*)wg + NG4_ + j;
  }
  const float4 v = *src;
  bf16x4 o = {(bf16_t)v.x, (bf16_t)v.y, (bf16_t)v.z, (bf16_t)v.w};
  *dst = o;
}

// ---------------- gates GEMV: one block per (b,t) --------------------------
__global__ __launch_bounds__(256) void gates_kernel(
    const bf16_t* __restrict__ x_bf, const bf16_t* __restrict__ wg,
    float* __restrict__ attn_gate, float* __restrict__ ve_gate2)
{
  const int bt = blockIdx.x;
  const int tid = threadIdx.x;
  __shared__ float xs[D_];
  {
    const bf16x4 xv = ((const bf16x4*)(x_bf + (size_t)bt * D_))[tid];
    xs[tid * 4 + 0] = (float)xv[0];
    xs[tid * 4 + 1] = (float)xv[1];
    xs[tid * 4 + 2] = (float)xv[2];
    xs[tid * 4 + 3] = (float)xv[3];
  }
  __syncthreads();
  const int g = tid >> 3, cg = tid & 7;
  const bf16x8* wrow = (const bf16x8*)(wg + (size_t)g * D_);
  float sum = 0.f;
#pragma unroll
  for (int j = 0; j < 16; ++j) {
    const bf16x8 w8 = wrow[cg + 8 * j];
    const float* xp = &xs[(cg + 8 * j) * 8];
#pragma unroll
    for (int e = 0; e < 8; ++e) sum = fmaf((float)w8[e], xp[e], sum);
  }
  sum += __shfl_xor(sum, 1);
  sum += __shfl_xor(sum, 2);
  sum += __shfl_xor(sum, 4);
  if (cg == 0) {
    const float sg = 1.f / (1.f + __expf(-sum));
    if (g < 16) attn_gate[bt * H_ + g] = sg;
    else        ve_gate2[bt * H_ + (g - 16)] = VE_SCALE_ * sg;
  }
}

// ------- QKV GEMM: 128x128 tile, BK=32 2-phase dbuf, 8 WAVES (512 thr) -----
// Same tile/FETCH as the r14 4-wave cell (59 us, 37.6 MB); waves/block
// doubled so 768 blocks give 24 waves/CU (vs 12) to hide the per-K-step
// vmcnt drain. Wave = 32x64 sub-tile (acc[2][4], ~70 VGPR); wave w stages
// A rows [w*16,+16) and B rows [w*16,+16) (2 gl_lds each).
// Epilogue fuses rmsnorm/rotary (q,k) + ve-augment (v); wave's 64-col
// group = one head. Writes q/k/v bf16 in (B,H,T,HD).
__global__ __launch_bounds__(512) void gemm_qkv(
    const bf16_t* __restrict__ A, const bf16_t* __restrict__ W,
    const float* __restrict__ ve, const float* __restrict__ cosb,
    const float* __restrict__ sinb, const float* __restrict__ ve_gate2,
    bf16_t* __restrict__ q_bf, bf16_t* __restrict__ k_bf,
    bf16_t* __restrict__ v_bf, int K,
    const float* __restrict__ lam)
{
  const float scale = lam[0];
  __shared__ bf16_t As[2][128][32];
  __shared__ bf16_t Bs[2][128][32];
  const int tid = threadIdx.x;
  const int lane = tid & 63, w = tid >> 6;       // w in 0..7
  const int lr = lane & 15, lg = lane >> 4;
  const int wr = w >> 1, wc = w & 1;             // 4x2 wave grid; wave=32x64

  const int nwg = gridDim.x * gridDim.y;   // 24*32 = 768 (%8==0, no tail)
  int bid = blockIdx.y * gridDim.x + blockIdx.x;
  bid = (bid & 7) * (nwg >> 3) + (bid >> 3);
  const int row0 = (bid / gridDim.x) * 128;
  const int col0 = (bid % gridDim.x) * 128;

  // staging: wave w covers rows [w*16, +16) of both A and B tiles
  const int srow = w * 16 + (lane >> 2);
  const int scol = (lane & 3) * 8;
  const bf16_t* Ag = A + (size_t)(row0 + srow) * K + scol;
  const bf16_t* Wg = W + (size_t)(col0 + srow) * K + scol;

  f32x4 acc[2][4];
#pragma unroll
  for (int i = 0; i < 2; ++i)
#pragma unroll
    for (int j = 0; j < 4; ++j) acc[i][j] = F4ZERO;

#define STAGE_(bi, kk)                            \
  do {                                            \
    gl_lds16(Ag + (kk), &As[bi][w * 16][0]);      \
    gl_lds16(Wg + (kk), &Bs[bi][w * 16][0]);      \
  } while (0)

#define COMPUTE_(bi)                                                     \
  do {                                                                   \
    bf16x8 af[2], bfr[4];                                                \
    _Pragma("unroll")                                                    \
    for (int fm = 0; fm < 2; ++fm)                                       \
      af[fm] = *(const bf16x8*)&As[bi][wr * 32 + fm * 16 + lr][lg * 8];  \
    _Pragma("unroll")                                                    \
    for (int fn = 0; fn < 4; ++fn)                                       \
      bfr[fn] = *(const bf16x8*)&Bs[bi][wc * 64 + fn * 16 + lr][lg * 8]; \
    _Pragma("unroll")                                                    \
    for (int fm = 0; fm < 2; ++fm)                                       \
      _Pragma("unroll")                                                  \
      for (int fn = 0; fn < 4; ++fn)                                     \
        acc[fm][fn] = __builtin_amdgcn_mfma_f32_16x16x32_bf16(           \
            af[fm], bfr[fn], acc[fm][fn], 0, 0, 0);                      \
  } while (0)

  STAGE_(0, 0);
  __syncthreads();
  for (int k0 = 0; k0 + 64 <= K; k0 += 64) {
    STAGE_(1, k0 + 32);
    COMPUTE_(0);
    __syncthreads();
    if (k0 + 64 < K) STAGE_(0, k0 + 64);
    COMPUTE_(1);
    __syncthreads();
  }
#undef STAGE_
#undef COMPUTE_

  // fused epilogue: col = wc*64 + fn*16 + lr; row = wr*32 + fm*16 + lg*4 + r
  const int sec = col0 >> 10;              // 0=q, 1=k, 2=v
  const int h = ((col0 & 1023) >> 6) + wc; // wave's head
#pragma unroll
  for (int fm = 0; fm < 2; ++fm) {
#pragma unroll
    for (int r = 0; r < 4; ++r) {
      const int row = row0 + wr * 32 + fm * 16 + lg * 4 + r;  // bt index
      const int b = row >> 11, t = row & (T_ - 1);
      float v0 = acc[fm][0][r] * scale;
      float v1 = acc[fm][1][r] * scale;
      float v2 = acc[fm][2][r] * scale;
      float v3 = acc[fm][3][r] * scale;
      const size_t obase = ((size_t)(b * H_ + h) * T_ + t) * HD_;
      if (sec < 2) {
        float ssq = v0 * v0 + v1 * v1 + v2 * v2 + v3 * v3;
        ssq += __shfl_xor(ssq, 1);
        ssq += __shfl_xor(ssq, 2);
        ssq += __shfl_xor(ssq, 4);
        ssq += __shfl_xor(ssq, 8);
        const float rn = rsqrtf(ssq * (1.f / 64.f) + EPS_);
        v0 *= rn; v1 *= rn; v2 *= rn; v3 *= rn;
        const float c0 = cosb[t * 32 + lr], s0 = sinb[t * 32 + lr];
        const float c1 = cosb[t * 32 + 16 + lr], s1 = sinb[t * 32 + 16 + lr];
        const float o0 = fmaf(v0, c0, v2 * s0);
        const float o2 = fmaf(v2, c0, -v0 * s0);
        const float o1 = fmaf(v1, c1, v3 * s1);
        const float o3 = fmaf(v3, c1, -v1 * s1);
        bf16_t* dst = (sec == 0 ? q_bf : k_bf);
        dst[obase + 0 + lr]  = (bf16_t)o0;
        dst[obase + 16 + lr] = (bf16_t)o1;
        dst[obase + 32 + lr] = (bf16_t)o2;
        dst[obase + 48 + lr] = (bf16_t)o3;
      } else {
        const float g = ve_gate2[row * H_ + h];
        const float* vp = ve + (size_t)row * D_ + h * HD_;
        v0 = fmaf(g, vp[0 + lr], v0);
        v1 = fmaf(g, vp[16 + lr], v1);
        v2 = fmaf(g, vp[32 + lr], v2);
        v3 = fmaf(g, vp[48 + lr], v3);
        v_bf[obase + 0 + lr]  = (bf16_t)v0;
        v_bf[obase + 16 + lr] = (bf16_t)v1;
        v_bf[obase + 32 + lr] = (bf16_t)v2;
        v_bf[obase + 48 + lr] = (bf16_t)v3;
      }
    }
  }
}

// ------- out-projection GEMM: 64x128 tile, 2-phase dbuf (r15: 2 blocks/CU,
// saved ~7.6 us vs 128x128's 1 block/CU at N=1024), f32 out ----------------
__global__ __launch_bounds__(256) void gemm_bf16(
    const bf16_t* __restrict__ A, const bf16_t* __restrict__ W,
    float* __restrict__ Cout, int M, int N, int K,
    const float* __restrict__ lam, int li)
{
  const float scale = lam[li];
  __shared__ bf16_t As[2][64][32];
  __shared__ bf16_t Bs[2][128][32];
  const int tid = threadIdx.x;
  const int lane = tid & 63, w = tid >> 6;
  const int lr = lane & 15, lg = lane >> 4;
  const int wr = w >> 1, wc = w & 1;

  const int nwg = gridDim.x * gridDim.y;
  int bid = blockIdx.y * gridDim.x + blockIdx.x;
  bid = (bid & 7) * (nwg >> 3) + (bid >> 3);
  const int row0 = (bid / gridDim.x) * 64;
  const int col0 = (bid % gridDim.x) * 128;

  const int srow = lane >> 2;
  const int scol = (lane & 3) * 8;
  const bf16_t* Ag  = A + (size_t)(row0 + w * 16 + srow) * K + scol;
  const bf16_t* Wg0 = W + (size_t)(col0 + w * 16 + srow) * K + scol;
  const bf16_t* Wg1 = Wg0 + (size_t)64 * K;

  f32x4 acc[2][4];
#pragma unroll
  for (int i = 0; i < 2; ++i)
#pragma unroll
    for (int j = 0; j < 4; ++j) acc[i][j] = F4ZERO;

#define STAGE_(bi, kk)                                \
  do {                                                \
    gl_lds16(Ag + (kk), &As[bi][w * 16][0]);          \
    gl_lds16(Wg0 + (kk), &Bs[bi][w * 16][0]);         \
    gl_lds16(Wg1 + (kk), &Bs[bi][64 + w * 16][0]);    \
  } while (0)

#define COMPUTE_(bi)                                                     \
  do {                                                                   \
    bf16x8 af[2], bfr[4];                                                \
    _Pragma("unroll")                                                    \
    for (int fm = 0; fm < 2; ++fm)                                       \
      af[fm] = *(const bf16x8*)&As[bi][wr * 32 + fm * 16 + lr][lg * 8];  \
    _Pragma("unroll")                                                    \
    for (int fn = 0; fn < 4; ++fn)                                       \
      bfr[fn] = *(const bf16x8*)&Bs[bi][wc * 64 + fn * 16 + lr][lg * 8]; \
    _Pragma("unroll")                                                    \
    for (int fm = 0; fm < 2; ++fm)                                       \
      _Pragma("unroll")                                                  \
      for (int fn = 0; fn < 4; ++fn)                                     \
        acc[fm][fn] = __builtin_amdgcn_mfma_f32_16x16x32_bf16(           \
            af[fm], bfr[fn], acc[fm][fn], 0, 0, 0);                      \
  } while (0)

  STAGE_(0, 0);
  __syncthreads();
  for (int k0 = 0; k0 + 64 <= K; k0 += 64) {
    STAGE_(1, k0 + 32);
    COMPUTE_(0);
    __syncthreads();
    if (k0 + 64 < K) STAGE_(0, k0 + 64);
    COMPUTE_(1);
    __syncthreads();
  }
#undef STAGE_
#undef COMPUTE_

#pragma unroll
  for (int fm = 0; fm < 2; ++fm)
#pragma unroll
    for (int fn = 0; fn < 4; ++fn)
#pragma unroll
      for (int r = 0; r < 4; ++r) {
        const int row = row0 + wr * 32 + fm * 16 + lg * 4 + r;
        const int col = col0 + wc * 64 + fn * 16 + lr;
        Cout[(size_t)row * N + col] = acc[fm][fn][r] * scale;
      }
}

// ---------------- MFMA flash attention, doc-block-diagonal ----------------
__global__ __launch_bounds__(256) void attn_mfma(
    const bf16_t* __restrict__ q_buf, const bf16_t* __restrict__ k_tmp,
    const bf16_t* __restrict__ v_buf, const float* __restrict__ attn_gate,
    const int* __restrict__ docs, const float* __restrict__ scale_ptr,
    bf16_t* __restrict__ y_buf)
{
  const int qt = blockIdx.x, bh = blockIdx.y;
  const int b = bh >> 4, h = bh & 15;
  const int tid = threadIdx.x;
  const int w = tid >> 6, lane = tid & 63;
  const int lr = lane & 15, lg = lane >> 4;
  const float scale = scale_ptr[0];
  __shared__ bf16_t Ks[64][72];
  __shared__ bf16_t Vt[64][72];
  __shared__ bf16_t Ps[64][72];
  __shared__ int dk[64];

  const int dlo = docs[qt * 64];
  const unsigned long long bal =
      __ballot((lane <= qt) && (docs[lane * 64 + 63] >= dlo));
  const int ktlo = __ffsll(bal) - 1;

  const bf16_t* qp = q_buf + ((size_t)bh * T_ + qt * 64 + w * 16 + lr) * HD_;
  const bf16x8 aq0 = *(const bf16x8*)(qp + lg * 8);
  const bf16x8 aq1 = *(const bf16x8*)(qp + 32 + lg * 8);
  int qpos_r[4], docq_r[4];
#pragma unroll
  for (int r = 0; r < 4; ++r) {
    qpos_r[r] = qt * 64 + w * 16 + lg * 4 + r;
    docq_r[r] = docs[qpos_r[r]];
  }
  f32x4 acc[4];
#pragma unroll
  for (int fn = 0; fn < 4; ++fn) acc[fn] = F4ZERO;
  float m[4] = {-1e30f, -1e30f, -1e30f, -1e30f};
  float l[4] = {0.f, 0.f, 0.f, 0.f};

#pragma unroll 1
  for (int kt = ktlo; kt <= qt; ++kt) {
    __syncthreads();
#pragma unroll
    for (int i = 0; i < 2; ++i) {
      const int idx = i * 256 + tid;
      const int krow = idx >> 3;
      const int c8 = (idx & 7) << 3;
      const int gk = kt * 64 + krow;
      const int gks = (((c8 & 16) != 0) && gk > 0) ? gk - 1 : gk;
      *(bf16x8*)&Ks[krow][c8] =
          *(const bf16x8*)(k_tmp + ((size_t)bh * T_ + gks) * HD_ + c8);
      const int kpos = idx & 63;
      const int d0 = (idx >> 6) << 3;
      const bf16x8 vv =
          *(const bf16x8*)(v_buf + ((size_t)bh * T_ + kt * 64 + kpos) * HD_ + d0);
#pragma unroll
      for (int j = 0; j < 8; ++j) Vt[d0 + j][kpos] = vv[j];
    }
    if (tid < 64) dk[tid] = docs[kt * 64 + tid];
    __syncthreads();

    f32x4 s[4];
#pragma unroll
    for (int fn = 0; fn < 4; ++fn) {
      const bf16x8 bk0 = *(const bf16x8*)&Ks[fn * 16 + lr][lg * 8];
      const bf16x8 bk1 = *(const bf16x8*)&Ks[fn * 16 + lr][32 + lg * 8];
      f32x4 z = F4ZERO;
      z = __builtin_amdgcn_mfma_f32_16x16x32_bf16(aq0, bk0, z, 0, 0, 0);
      s[fn] = __builtin_amdgcn_mfma_f32_16x16x32_bf16(aq1, bk1, z, 0, 0, 0);
    }
    const bool strict = (kt < qt);
#pragma unroll
    for (int fn = 0; fn < 4; ++fn) {
      const int kd = dk[fn * 16 + lr];
      const int kp = kt * 64 + fn * 16 + lr;
#pragma unroll
      for (int r = 0; r < 4; ++r) {
        const bool valid = (kd == docq_r[r]) && (strict || kp <= qpos_r[r]);
        s[fn][r] = valid ? s[fn][r] * scale : -3.0e38f;
      }
    }
#pragma unroll
    for (int r = 0; r < 4; ++r) {
      float cm = fmaxf(fmaxf(s[0][r], s[1][r]), fmaxf(s[2][r], s[3][r]));
      cm = fmaxf(cm, __shfl_xor(cm, 1));
      cm = fmaxf(cm, __shfl_xor(cm, 2));
      cm = fmaxf(cm, __shfl_xor(cm, 4));
      cm = fmaxf(cm, __shfl_xor(cm, 8));
      const float mn = fmaxf(m[r], cm);
      const float sc = __expf(m[r] - mn);
      m[r] = mn;
      const float p0 = __expf(s[0][r] - mn);
      const float p1 = __expf(s[1][r] - mn);
      const float p2 = __expf(s[2][r] - mn);
      const float p3 = __expf(s[3][r] - mn);
      float ps = (p0 + p1) + (p2 + p3);
      ps += __shfl_xor(ps, 1);
      ps += __shfl_xor(ps, 2);
      ps += __shfl_xor(ps, 4);
      ps += __shfl_xor(ps, 8);
      l[r] = l[r] * sc + ps;
      acc[0][r] *= sc; acc[1][r] *= sc; acc[2][r] *= sc; acc[3][r] *= sc;
      const int prow = w * 16 + lg * 4 + r;
      Ps[prow][0 + lr]  = (bf16_t)p0;
      Ps[prow][16 + lr] = (bf16_t)p1;
      Ps[prow][32 + lr] = (bf16_t)p2;
      Ps[prow][48 + lr] = (bf16_t)p3;
    }
    const bf16x8 ap0 = *(const bf16x8*)&Ps[w * 16 + lr][lg * 8];
    const bf16x8 ap1 = *(const bf16x8*)&Ps[w * 16 + lr][32 + lg * 8];
#pragma unroll
    for (int fn = 0; fn < 4; ++fn) {
      const bf16x8 bv0 = *(const bf16x8*)&Vt[fn * 16 + lr][lg * 8];
      const bf16x8 bv1 = *(const bf16x8*)&Vt[fn * 16 + lr][32 + lg * 8];
      acc[fn] = __builtin_amdgcn_mfma_f32_16x16x32_bf16(ap0, bv0, acc[fn], 0, 0, 0);
      acc[fn] = __builtin_amdgcn_mfma_f32_16x16x32_bf16(ap1, bv1, acc[fn], 0, 0, 0);
    }
  }
#pragma unroll
  for (int r = 0; r < 4; ++r) {
    const float inv = attn_gate[(size_t)(b * T_ + qpos_r[r]) * H_ + h] / l[r];
#pragma unroll
    for (int fn = 0; fn < 4; ++fn)
      y_buf[(size_t)(b * T_ + qpos_r[r]) * D_ + h * HD_ + fn * 16 + lr] =
          (bf16_t)(acc[fn][r] * inv);
  }
}

extern "C" void kernel_launch(void* const* d_in, const int* in_sizes, int n_in,
                              void* d_out, int out_size, void* d_ws, size_t ws_size,
                              hipStream_t stream) {
  const float* x    = (const float*)d_in[0];
  const float* ve   = (const float*)d_in[1];
  const float* lam  = (const float*)d_in[2];
  const float* cosb = (const float*)d_in[3];
  const float* sinb = (const float*)d_in[4];
  const float* qkvo = (const float*)d_in[5];
  const float* agw  = (const float*)d_in[6];
  const float* vgw  = (const float*)d_in[7];
  const float* ascl = (const float*)d_in[8];
  const int*   docs = (const int*)d_in[9];
  float* out = (float*)d_out;

  const size_t BT = (size_t)B_ * T_;  // 4096
  float* cur = (float*)d_ws;
  bf16_t* x_bf = (bf16_t*)cur;        cur += BT * D_ / 2;
  bf16_t* wq_bf = (bf16_t*)cur;       cur += (size_t)3 * D_ * D_ / 2;
  bf16_t* wo_bf = (bf16_t*)cur;       cur += (size_t)D_ * D_ / 2;
  bf16_t* wg_bf = (bf16_t*)cur;       cur += (size_t)2 * H_ * D_ / 2;
  bf16_t* q_bf = (bf16_t*)cur;        cur += BT * D_ / 2;
  bf16_t* k_bf = (bf16_t*)cur;        cur += BT * D_ / 2;
  bf16_t* v_bf = (bf16_t*)cur;        cur += BT * D_ / 2;
  bf16_t* y_bf = (bf16_t*)cur;        cur += BT * D_ / 2;
  float* attn_gate = cur;             cur += BT * H_;
  float* ve_gate2 = cur;              cur += BT * H_;

  // 0) single fused cast: x, wq, wo, wg (gate weights)
  cast_all<<<(NX4_ + NQ4_ + 2 * NG4_) / 256, 256, 0, stream>>>(
      x, qkvo, agw, vgw, x_bf, wq_bf, wo_bf, wg_bf);

  // 1) gates GEMV (attn-gate sigmoid, ve-gate 2*sigmoid)
  gates_kernel<<<(int)BT, 256, 0, stream>>>(x_bf, wg_bf, attn_gate, ve_gate2);

  // 2) QKV + fused rmsnorm/rotary/v-augment — 768 blocks x 8 waves (24 w/CU)
  gemm_qkv<<<dim3(3 * D_ / 128, BT / 128), 512, 0, stream>>>(
      x_bf, wq_bf, ve, cosb, sinb, ve_gate2, q_bf, k_bf, v_bf, D_, lam);

  // 3) MFMA flash attention (doc-block-diagonal skip; key-offset fused)
  attn_mfma<<<dim3(T_ / 64, B_ * H_), 256, 0, stream>>>(
      q_bf, k_bf, v_bf, attn_gate, docs, ascl, y_bf);

  // 4) output projection (64x128 tile, 512 blocks = 2/CU, f32 out)
  gemm_bf16<<<dim3(D_ / 128, BT / 64), 256, 0, stream>>>(
      y_bf, wo_bf, out, (int)BT, D_, D_, lam, 1);
}